// Round 1
// baseline (197.442 us; speedup 1.0000x reference)
//
#include <hip/hip_runtime.h>

// Problem constants (from reference): B=8, S=2048, D=512, G=2, V=320, CV=128
#define M_ROWS 16384   // B*S
#define K_DIM  512     // d_model
#define N_COLS 640     // G*V
#define V_CODES 320
#define CV_DIM 128
#define R_ROWS 32768   // M_ROWS * G
#define NPART  512     // blocks in rowops kernel

// ---------------------------------------------------------------------------
// Kernel 1: logits = hs @ W + b   (f32, M=16384, K=512, N=640)
// Tile: BM=64, BN=128, BK=16; 256 threads; 4x8 micro-tile per thread.
// ---------------------------------------------------------------------------
__global__ __launch_bounds__(256)
void gemm_bias_f32(const float* __restrict__ A, const float* __restrict__ B,
                   const float* __restrict__ bias, float* __restrict__ C) {
    __shared__ float As[16][64];    // [k][m] transposed
    __shared__ float Bs[16][128];   // [k][n]
    const int bn = blockIdx.x;      // 0..4  (640/128)
    const int bm = blockIdx.y;      // 0..255 (16384/64)
    const int t  = threadIdx.x;
    const int tm = t >> 4;          // 0..15 -> rows of 4
    const int tn = t & 15;          // 0..15 -> cols of 8

    const int arow = t >> 2;            // 0..63
    const int acol = (t & 3) << 2;      // 0,4,8,12
    const int brow = t >> 4;            // 0..15
    const int bcol = (t & 15) << 3;     // 0..120

    const float* Ab = A + (size_t)bm * 64 * K_DIM;
    const float* Bb = B + bn * 128;

    float acc[4][8];
#pragma unroll
    for (int i = 0; i < 4; ++i)
#pragma unroll
        for (int j = 0; j < 8; ++j) acc[i][j] = 0.f;

    for (int k0 = 0; k0 < K_DIM; k0 += 16) {
        float4 av = *(const float4*)(Ab + (size_t)arow * K_DIM + k0 + acol);
        float4 bv0 = *(const float4*)(Bb + (size_t)(k0 + brow) * N_COLS + bcol);
        float4 bv1 = *(const float4*)(Bb + (size_t)(k0 + brow) * N_COLS + bcol + 4);
        __syncthreads();
        As[acol + 0][arow] = av.x;
        As[acol + 1][arow] = av.y;
        As[acol + 2][arow] = av.z;
        As[acol + 3][arow] = av.w;
        *(float4*)&Bs[brow][bcol]     = bv0;
        *(float4*)&Bs[brow][bcol + 4] = bv1;
        __syncthreads();
#pragma unroll
        for (int k = 0; k < 16; ++k) {
            float4 a  = *(const float4*)&As[k][tm << 2];
            float4 b0 = *(const float4*)&Bs[k][tn << 3];
            float4 b1 = *(const float4*)&Bs[k][(tn << 3) + 4];
            float ar[4] = {a.x, a.y, a.z, a.w};
            float br[8] = {b0.x, b0.y, b0.z, b0.w, b1.x, b1.y, b1.z, b1.w};
#pragma unroll
            for (int i = 0; i < 4; ++i)
#pragma unroll
                for (int j = 0; j < 8; ++j)
                    acc[i][j] = fmaf(ar[i], br[j], acc[i][j]);
        }
    }

    const int row0 = bm * 64 + (tm << 2);
    const int col0 = bn * 128 + (tn << 3);
    float4 bb0 = *(const float4*)(bias + col0);
    float4 bb1 = *(const float4*)(bias + col0 + 4);
#pragma unroll
    for (int i = 0; i < 4; ++i) {
        float4 o0 = {acc[i][0] + bb0.x, acc[i][1] + bb0.y,
                     acc[i][2] + bb0.z, acc[i][3] + bb0.w};
        float4 o1 = {acc[i][4] + bb1.x, acc[i][5] + bb1.y,
                     acc[i][6] + bb1.z, acc[i][7] + bb1.w};
        float* crow = C + (size_t)(row0 + i) * N_COLS + col0;
        *(float4*)(crow)     = o0;
        *(float4*)(crow + 4) = o1;
    }
}

// ---------------------------------------------------------------------------
// Kernel 2: per-row argmax(logits+gumbels) -> gather codevector;
// noise-free softmax accumulated into per-block marginal partials.
// 512 blocks x 256 threads; each wave handles 16 rows sequentially.
// ---------------------------------------------------------------------------
__global__ __launch_bounds__(256)
void rowops(const float* __restrict__ logits, const float* __restrict__ gum,
            const float* __restrict__ cv, float* __restrict__ out,
            float* __restrict__ partials) {
    __shared__ float marg[4][640];   // wave-private partial marginals [wave][g*V+v]
    const int t = threadIdx.x;
    const int wave = t >> 6, lane = t & 63;

    for (int i = t; i < 4 * 640; i += 256) ((float*)marg)[i] = 0.f;
    __syncthreads();

    const int r0 = blockIdx.x * 64 + wave * 16;
    for (int i = 0; i < 16; ++i) {
        const int r = r0 + i;
        const int g = r & 1;
        const float* lrow = logits + (size_t)r * V_CODES;
        const float* grow = gum + (size_t)r * V_CODES;

        float lv[5];
        float bestv = -1e30f;
        int   besti = 0;
        float lmax = -1e30f;
#pragma unroll
        for (int j = 0; j < 5; ++j) {
            const int v = lane + 64 * j;
            const float L = lrow[v];
            const float Nz = L + grow[v];
            lv[j] = L;
            if (Nz > bestv) { bestv = Nz; besti = v; }
            lmax = fmaxf(lmax, L);
        }
        // wave-wide argmax (tie -> lowest index, matches jnp.argmax) + max
#pragma unroll
        for (int off = 32; off; off >>= 1) {
            const float ov = __shfl_down(bestv, off);
            const int   oi = __shfl_down(besti, off);
            if (ov > bestv || (ov == bestv && oi < besti)) { bestv = ov; besti = oi; }
            lmax = fmaxf(lmax, __shfl_down(lmax, off));
        }
        besti = __shfl(besti, 0);
        lmax  = __shfl(lmax, 0);

        // noise-free softmax -> marginal partial
        float ex[5];
        float sum = 0.f;
#pragma unroll
        for (int j = 0; j < 5; ++j) { ex[j] = __expf(lv[j] - lmax); sum += ex[j]; }
#pragma unroll
        for (int off = 32; off; off >>= 1) sum += __shfl_down(sum, off);
        sum = __shfl(sum, 0);
        const float inv = 1.f / sum;
#pragma unroll
        for (int j = 0; j < 5; ++j)
            marg[wave][g * V_CODES + lane + 64 * j] += ex[j] * inv;

        // straight-through output == one-hot gather of the codevector
        const int n = r >> 1;
        const float2 cvv =
            ((const float2*)(cv + ((size_t)g * V_CODES + besti) * CV_DIM))[lane];
        ((float2*)(out + (size_t)n * 256 + g * CV_DIM))[lane] = cvv;
    }
    __syncthreads();

    float* p = partials + (size_t)blockIdx.x * 640;
    for (int i = t; i < 640; i += 256)
        p[i] = marg[0][i] + marg[1][i] + marg[2][i] + marg[3][i];
}

// ---------------------------------------------------------------------------
// Kernel 3: finalize perplexity from marginal partials.
// ---------------------------------------------------------------------------
__global__ __launch_bounds__(640)
void finalize(const float* __restrict__ partials, float* __restrict__ perp_out) {
    __shared__ float terms[640];
    __shared__ float gsum[2];
    const int t = threadIdx.x;

    float s = 0.f;
    for (int b = 0; b < NPART; ++b) s += partials[(size_t)b * 640 + t];
    const float m = s * (1.0f / (float)M_ROWS);
    terms[t] = -m * __logf(m + 1e-7f);
    __syncthreads();

    if (t < 128) {
        const int g = t >> 6, lane = t & 63;
        float e = 0.f;
#pragma unroll
        for (int j = 0; j < 5; ++j) e += terms[g * V_CODES + lane + 64 * j];
#pragma unroll
        for (int off = 32; off; off >>= 1) e += __shfl_down(e, off);
        if (lane == 0) gsum[g] = e;
    }
    __syncthreads();
    if (t == 0) perp_out[0] = __expf(gsum[0]) + __expf(gsum[1]);
}

// ---------------------------------------------------------------------------
extern "C" void kernel_launch(void* const* d_in, const int* in_sizes, int n_in,
                              void* d_out, int out_size, void* d_ws, size_t ws_size,
                              hipStream_t stream) {
    (void)in_sizes; (void)n_in; (void)out_size; (void)ws_size;
    const float* hs = (const float*)d_in[0];   // (8,2048,512)
    const float* W  = (const float*)d_in[1];   // (512,640)
    const float* bi = (const float*)d_in[2];   // (640,)
    const float* cv = (const float*)d_in[3];   // (1,640,128)
    const float* gu = (const float*)d_in[4];   // (32768,320)
    float* out = (float*)d_out;                // 16384*256 floats + 1 (perplexity)

    float* logits   = (float*)d_ws;                          // 16384*640 f32 = 41.9 MB
    float* partials = logits + (size_t)M_ROWS * N_COLS;      // 512*640 f32  = 1.3 MB

    dim3 g1(5, 256);     // (N/128, M/64)
    gemm_bias_f32<<<g1, 256, 0, stream>>>(hs, W, bi, logits);

    rowops<<<NPART, 256, 0, stream>>>(logits, gu, cv, out, partials);

    finalize<<<1, 640, 0, stream>>>(partials, out + (size_t)M_ROWS * 256);
}

// Round 2
// 82.303 us; speedup vs baseline: 2.3990x; 2.3990x over previous
//
#include <hip/hip_runtime.h>

// Problem constants: B=8, S=2048, D=512, G=2, V=320, CV=128
#define M_ROWS 16384   // B*S
#define K_DIM  512
#define N_COLS 640     // G*V
#define V_CODES 320
#define CV_DIM 128

typedef _Float16 half8 __attribute__((ext_vector_type(8)));
typedef _Float16 half4 __attribute__((ext_vector_type(4)));
typedef float floatx4 __attribute__((ext_vector_type(4)));

__device__ inline void gll16(const void* g, void* l) {
    __builtin_amdgcn_global_load_lds(
        (const __attribute__((address_space(1))) void*)g,
        (__attribute__((address_space(3))) void*)l, 16, 0, 0);
}

// ---------------------------------------------------------------------------
// Kernel 0: prep — A f32->f16, W (K,N) -> Wt (N,K) f16, zero marginal[640]
// ---------------------------------------------------------------------------
__global__ __launch_bounds__(256)
void prep(const float* __restrict__ A, const float* __restrict__ W,
          _Float16* __restrict__ Af, _Float16* __restrict__ Wt,
          float* __restrict__ marginal) {
    const int b = blockIdx.x, t = threadIdx.x;
    if (b < 2048) {
        const float4* A4 = (const float4*)A;
        half4* O4 = (half4*)Af;
        const size_t gid = (size_t)b * 256 + t;
#pragma unroll
        for (int it = 0; it < 4; ++it) {
            size_t i = (size_t)it * 524288 + gid;   // 2,097,152 float4 total
            float4 v = A4[i];
            half4 o = {(_Float16)v.x, (_Float16)v.y, (_Float16)v.z, (_Float16)v.w};
            O4[i] = o;
        }
    } else if (b < 2088) {
        const int lid = (b - 2048) * 256 + t;       // 0..10239
        const int n  = lid >> 4;                    // 0..639
        const int k0 = (lid & 15) * 32;             // 0..480
#pragma unroll
        for (int j = 0; j < 32; ++j)
            Wt[(size_t)n * 512 + k0 + j] = (_Float16)W[(size_t)(k0 + j) * 640 + n];
    } else {
        for (int i = t; i < 640; i += 256) marginal[i] = 0.f;
    }
}

// ---------------------------------------------------------------------------
// Kernel 1: MFMA f16 GEMM  logits = A @ Wt^T + bias  -> f16 logits
// 128x128 tile, BK=64, 4 waves (2x2 of 64x64), 16x16x32_f16 fragments.
// global_load_lds staging with XOR-swizzled global source (linear LDS dest),
// swizzled ds_read_b128 on the read side: byte ^= ((row&7)<<4).
// ---------------------------------------------------------------------------
__global__ __launch_bounds__(256)
void gemm_mfma(const _Float16* __restrict__ A, const _Float16* __restrict__ Bt,
               const float* __restrict__ bias, _Float16* __restrict__ C) {
    __shared__ _Float16 As[128 * 64];
    __shared__ _Float16 Bs[128 * 64];
    const int t = threadIdx.x;
    const int wave = t >> 6, lane = t & 63;
    const int bn = blockIdx.x, bm = blockIdx.y;
    const int wr = wave >> 1, wc = wave & 1;

    floatx4 acc[4][4];
#pragma unroll
    for (int i = 0; i < 4; ++i)
#pragma unroll
        for (int j = 0; j < 4; ++j) acc[i][j] = (floatx4){0.f, 0.f, 0.f, 0.f};

    const int m_st = t >> 3;     // 0..31  (row within 32-row staging group)
    const int c_st = t & 7;      // 16B chunk within 128B row

    const _Float16* Abase = A  + (size_t)(bm * 128) * 512;
    const _Float16* Bbase = Bt + (size_t)(bn * 128) * 512;

    for (int k0 = 0; k0 < 512; k0 += 64) {
#pragma unroll
        for (int r = 0; r < 4; ++r) {
            const int m  = r * 32 + m_st;
            const int lc = c_st ^ (m & 7);           // pre-swizzled source chunk
            gll16(Abase + (size_t)m * 512 + k0 + lc * 8,
                  (char*)As + r * 4096 + wave * 1024);
        }
#pragma unroll
        for (int r = 0; r < 4; ++r) {
            const int m  = r * 32 + m_st;
            const int lc = c_st ^ (m & 7);
            gll16(Bbase + (size_t)m * 512 + k0 + lc * 8,
                  (char*)Bs + r * 4096 + wave * 1024);
        }
        __syncthreads();   // drains vmcnt before barrier (compiler-inserted)

#pragma unroll
        for (int kk = 0; kk < 2; ++kk) {
            half8 af[4], bf[4];
#pragma unroll
            for (int mi = 0; mi < 4; ++mi) {
                const int ra = wr * 64 + mi * 16 + (lane & 15);
                const int j  = kk * 4 + (lane >> 4);
                af[mi] = *(const half8*)((const char*)As +
                           ra * 128 + ((j ^ (ra & 7)) * 16));
            }
#pragma unroll
            for (int ni = 0; ni < 4; ++ni) {
                const int rb = wc * 64 + ni * 16 + (lane & 15);
                const int j  = kk * 4 + (lane >> 4);
                bf[ni] = *(const half8*)((const char*)Bs +
                           rb * 128 + ((j ^ (rb & 7)) * 16));
            }
#pragma unroll
            for (int mi = 0; mi < 4; ++mi)
#pragma unroll
                for (int ni = 0; ni < 4; ++ni)
                    acc[mi][ni] = __builtin_amdgcn_mfma_f32_16x16x32_f16(
                        af[mi], bf[ni], acc[mi][ni], 0, 0, 0);
        }
        __syncthreads();   // protect LDS before next stage
    }

    const int row0 = bm * 128 + wr * 64;
    const int col0 = bn * 128 + wc * 64;
#pragma unroll
    for (int ni = 0; ni < 4; ++ni) {
        const int col = col0 + ni * 16 + (lane & 15);
        const float bv = bias[col];
#pragma unroll
        for (int mi = 0; mi < 4; ++mi) {
#pragma unroll
            for (int rg = 0; rg < 4; ++rg) {
                const int row = row0 + mi * 16 + (lane >> 4) * 4 + rg;
                C[(size_t)row * 640 + col] = (_Float16)(acc[mi][ni][rg] + bv);
            }
        }
    }
}

// ---------------------------------------------------------------------------
// Kernel 2: per-row argmax(logits+gumbels) -> codevector gather;
// noise-free softmax accumulated into global marginal via atomics.
// ---------------------------------------------------------------------------
__global__ __launch_bounds__(256)
void rowops(const _Float16* __restrict__ logits, const float* __restrict__ gum,
            const float* __restrict__ cv, float* __restrict__ out,
            float* __restrict__ marginal) {
    __shared__ float marg[4][640];
    const int t = threadIdx.x;
    const int wave = t >> 6, lane = t & 63;

    for (int i = t; i < 4 * 640; i += 256) ((float*)marg)[i] = 0.f;
    __syncthreads();

    const int r0 = blockIdx.x * 64 + wave * 16;
    for (int i = 0; i < 16; ++i) {
        const int r = r0 + i;
        const int g = r & 1;
        const _Float16* lrow = logits + (size_t)r * V_CODES;
        const float* grow = gum + (size_t)r * V_CODES;

        float lv[5];
        float bestv = -1e30f;
        int   besti = 0;
        float lmax = -1e30f;
#pragma unroll
        for (int j = 0; j < 5; ++j) {
            const int v = lane + 64 * j;
            const float L = (float)lrow[v];
            const float Nz = L + grow[v];
            lv[j] = L;
            if (Nz > bestv) { bestv = Nz; besti = v; }
            lmax = fmaxf(lmax, L);
        }
#pragma unroll
        for (int off = 32; off; off >>= 1) {
            const float ov = __shfl_down(bestv, off);
            const int   oi = __shfl_down(besti, off);
            if (ov > bestv || (ov == bestv && oi < besti)) { bestv = ov; besti = oi; }
            lmax = fmaxf(lmax, __shfl_down(lmax, off));
        }
        besti = __shfl(besti, 0);
        lmax  = __shfl(lmax, 0);

        float ex[5];
        float sum = 0.f;
#pragma unroll
        for (int j = 0; j < 5; ++j) { ex[j] = __expf(lv[j] - lmax); sum += ex[j]; }
#pragma unroll
        for (int off = 32; off; off >>= 1) sum += __shfl_down(sum, off);
        sum = __shfl(sum, 0);
        const float inv = 1.f / sum;
#pragma unroll
        for (int j = 0; j < 5; ++j)
            marg[wave][g * V_CODES + lane + 64 * j] += ex[j] * inv;

        const int n = r >> 1;
        const float2 cvv =
            ((const float2*)(cv + ((size_t)g * V_CODES + besti) * CV_DIM))[lane];
        ((float2*)(out + (size_t)n * 256 + g * CV_DIM))[lane] = cvv;
    }
    __syncthreads();

    for (int i = t; i < 640; i += 256) {
        const float v = marg[0][i] + marg[1][i] + marg[2][i] + marg[3][i];
        atomicAdd(marginal + i, v);
    }
}

// ---------------------------------------------------------------------------
// Kernel 3: finalize perplexity from the global marginal (640 floats).
// ---------------------------------------------------------------------------
__global__ __launch_bounds__(640)
void finalize(const float* __restrict__ marginal, float* __restrict__ perp_out) {
    __shared__ float terms[640];
    __shared__ float gsum[2];
    const int t = threadIdx.x;

    const float m = marginal[t] * (1.0f / (float)M_ROWS);
    terms[t] = -m * __logf(m + 1e-7f);
    __syncthreads();

    if (t < 128) {
        const int g = t >> 6, lane = t & 63;
        float e = 0.f;
#pragma unroll
        for (int j = 0; j < 5; ++j) e += terms[g * V_CODES + lane + 64 * j];
#pragma unroll
        for (int off = 32; off; off >>= 1) e += __shfl_down(e, off);
        if (lane == 0) gsum[g] = e;
    }
    __syncthreads();
    if (t == 0) perp_out[0] = __expf(gsum[0]) + __expf(gsum[1]);
}

// ---------------------------------------------------------------------------
extern "C" void kernel_launch(void* const* d_in, const int* in_sizes, int n_in,
                              void* d_out, int out_size, void* d_ws, size_t ws_size,
                              hipStream_t stream) {
    (void)in_sizes; (void)n_in; (void)out_size; (void)ws_size;
    const float* hs = (const float*)d_in[0];   // (8,2048,512)
    const float* W  = (const float*)d_in[1];   // (512,640)
    const float* bi = (const float*)d_in[2];   // (640,)
    const float* cv = (const float*)d_in[3];   // (1,640,128)
    const float* gu = (const float*)d_in[4];   // (32768,320)
    float* out = (float*)d_out;

    // ws layout (total ~38.4 MB, under the proven 43.2 MB from round 1):
    _Float16* logitsH = (_Float16*)d_ws;                       // 16384*640 f16
    _Float16* Af      = logitsH + (size_t)M_ROWS * N_COLS;     // 16384*512 f16
    _Float16* Wt      = Af + (size_t)M_ROWS * K_DIM;           // 640*512 f16
    float*    marginal= (float*)(Wt + (size_t)N_COLS * K_DIM); // 640 f32

    prep<<<2089, 256, 0, stream>>>(hs, W, Af, Wt, marginal);
    gemm_mfma<<<dim3(5, 128), 256, 0, stream>>>(Af, Wt, bi, logitsH);
    rowops<<<512, 256, 0, stream>>>(logitsH, gu, cv, out, marginal);
    finalize<<<1, 640, 0, stream>>>(marginal, out + (size_t)M_ROWS * 256);
}

// Round 3
// 76.729 us; speedup vs baseline: 2.5733x; 1.0727x over previous
//
#include <hip/hip_runtime.h>

// Problem constants: B=8, S=2048, D=512, G=2, V=320, CV=128
#define M_ROWS 16384   // B*S
#define K_DIM  512
#define N_COLS 640     // G*V
#define V_CODES 320
#define CV_DIM 128

typedef _Float16 half8 __attribute__((ext_vector_type(8)));
typedef _Float16 half2v __attribute__((ext_vector_type(2)));
typedef float floatx4 __attribute__((ext_vector_type(4)));

__device__ inline void gll16(const void* g, void* l) {
    __builtin_amdgcn_global_load_lds(
        (const __attribute__((address_space(1))) void*)g,
        (__attribute__((address_space(3))) void*)l, 16, 0, 0);
}

// ---------------------------------------------------------------------------
// Kernel 0: prep — W (K,N) f32 -> Wt (N,K) f16; zero global marginal[640]
// ---------------------------------------------------------------------------
__global__ __launch_bounds__(256)
void prep(const float* __restrict__ W, _Float16* __restrict__ Wt,
          float* __restrict__ marginal) {
    const int b = blockIdx.x, t = threadIdx.x;
    if (b < 40) {
        const int lid = b * 256 + t;                // 0..10239
        const int n  = lid >> 4;                    // 0..639
        const int k0 = (lid & 15) * 32;             // 0..480
#pragma unroll
        for (int j = 0; j < 32; ++j)
            Wt[(size_t)n * 512 + k0 + j] = (_Float16)W[(size_t)(k0 + j) * 640 + n];
    } else {
        for (int i = t; i < 640; i += 256) marginal[i] = 0.f;
    }
}

// ---------------------------------------------------------------------------
// Kernel 1 (fused): per block, logits tile 32x640 = A(32xK) @ Wt^T + bias via
// MFMA (f16), tile kept in LDS; then in-block gumbel-argmax -> codevector
// gather, noise-free softmax -> marginal atomics. No logits HBM roundtrip.
//   8 waves x 64 lanes; wave w owns n-cols [w*80, w*80+80) (5 n-tiles x 2 m-tiles)
//   A: reg-staged f32 -> f16 with LDS XOR-swizzle (write+read same involution)
//   B: global_load_lds 16B, source pre-swizzled, linear LDS dest (rule #21)
// ---------------------------------------------------------------------------
union SMem {
    struct { _Float16 Bs[640 * 32]; _Float16 As[32 * 32]; } g;  // 40960 + 2048 B
    struct { _Float16 L[32 * 640];  float marg[640]; } e;        // 40960 + 2560 B
};

__global__ __launch_bounds__(512, 4)
void fused(const float* __restrict__ A, const _Float16* __restrict__ Wt,
           const float* __restrict__ bias, const float* __restrict__ gum,
           const float* __restrict__ cv, float* __restrict__ out,
           float* __restrict__ marginal) {
    __shared__ SMem sm;
    const int t = threadIdx.x;
    const int wave = t >> 6, lane = t & 63;
    const int bm = blockIdx.x;

    floatx4 acc[2][5];
#pragma unroll
    for (int mi = 0; mi < 2; ++mi)
#pragma unroll
        for (int ni = 0; ni < 5; ++ni) acc[mi][ni] = (floatx4){0.f, 0.f, 0.f, 0.f};

    // --- A staging mapping (reg-staged, f32->f16, swizzled ds_write) ---
    const int am = t >> 4;                       // row 0..31
    const int ak = (t & 15) * 2;                 // k element pair
    const int aj = (t & 15) >> 2;                // 16B chunk 0..3
    const int a_wr_off = am * 64 + ((aj ^ ((am >> 1) & 3)) << 4) + (t & 3) * 4;
    const float* Arow = A + (size_t)(bm * 32 + am) * 512 + ak;

    // --- K loop ---
    for (int k0 = 0; k0 < 512; k0 += 32) {
        // B stage: 2560 x 16B chunks, linear LDS dest, swizzled global source
#pragma unroll
        for (int s = 0; s < 5; ++s) {
            const int q = t + 512 * s;           // 0..2559
            const int n = q >> 2, j = q & 3;
            gll16(Wt + (size_t)n * 512 + k0 + ((j ^ ((n >> 1) & 3)) << 3),
                  (char*)sm.g.Bs + q * 16);
        }
        // A stage: load f32 pair, convert, swizzled LDS write
        {
            const float2 av = *(const float2*)(Arow + k0);
            const half2v ah = {(_Float16)av.x, (_Float16)av.y};
            *(half2v*)((char*)sm.g.As + a_wr_off) = ah;
        }
        __syncthreads();

        half8 af[2], bf[5];
#pragma unroll
        for (int mi = 0; mi < 2; ++mi) {
            const int ra = mi * 16 + (lane & 15);
            af[mi] = *(const half8*)((const char*)sm.g.As +
                       ra * 64 + ((((lane >> 4) ^ ((ra >> 1) & 3)) << 4)));
        }
#pragma unroll
        for (int ni = 0; ni < 5; ++ni) {
            const int nb = wave * 80 + ni * 16 + (lane & 15);
            bf[ni] = *(const half8*)((const char*)sm.g.Bs +
                       nb * 64 + ((((lane >> 4) ^ ((nb >> 1) & 3)) << 4)));
        }
#pragma unroll
        for (int mi = 0; mi < 2; ++mi)
#pragma unroll
            for (int ni = 0; ni < 5; ++ni)
                acc[mi][ni] = __builtin_amdgcn_mfma_f32_16x16x32_f16(
                    af[mi], bf[ni], acc[mi][ni], 0, 0, 0);
        __syncthreads();   // protects LDS for next stage AND epilogue overwrite
    }

    // --- epilogue: acc + bias -> LDS logits (f16) ---
#pragma unroll
    for (int ni = 0; ni < 5; ++ni) {
        const int col = wave * 80 + ni * 16 + (lane & 15);
        const float bv = bias[col];
#pragma unroll
        for (int mi = 0; mi < 2; ++mi) {
#pragma unroll
            for (int rg = 0; rg < 4; ++rg) {
                const int row = mi * 16 + (lane >> 4) * 4 + rg;
                sm.e.L[row * 640 + col] = (_Float16)(acc[mi][ni][rg] + bv);
            }
        }
    }
    for (int i = t; i < 640; i += 512) sm.e.marg[i] = 0.f;
    __syncthreads();

    // --- row phase: 4 M-rows per wave, both groups each ---
    float mreg[2][5];
#pragma unroll
    for (int g = 0; g < 2; ++g)
#pragma unroll
        for (int j = 0; j < 5; ++j) mreg[g][j] = 0.f;

    for (int i = 0; i < 4; ++i) {
        const int r = wave * 4 + i;
        const size_t n = (size_t)bm * 32 + r;
#pragma unroll
        for (int g = 0; g < 2; ++g) {
            const float* grow = gum + (n * 2 + g) * V_CODES;
            float lv[5];
            float bestv = -1e30f;
            int   besti = 0;
            float lmax = -1e30f;
#pragma unroll
            for (int j = 0; j < 5; ++j) {
                const int v = lane + 64 * j;
                const float L = (float)sm.e.L[r * 640 + g * V_CODES + v];
                const float Nz = L + grow[v];
                lv[j] = L;
                if (Nz > bestv) { bestv = Nz; besti = v; }
                lmax = fmaxf(lmax, L);
            }
#pragma unroll
            for (int off = 32; off; off >>= 1) {
                const float ov = __shfl_down(bestv, off);
                const int   oi = __shfl_down(besti, off);
                if (ov > bestv || (ov == bestv && oi < besti)) { bestv = ov; besti = oi; }
                lmax = fmaxf(lmax, __shfl_down(lmax, off));
            }
            besti = __shfl(besti, 0);
            lmax  = __shfl(lmax, 0);

            float ex[5];
            float sum = 0.f;
#pragma unroll
            for (int j = 0; j < 5; ++j) { ex[j] = __expf(lv[j] - lmax); sum += ex[j]; }
#pragma unroll
            for (int off = 32; off; off >>= 1) sum += __shfl_down(sum, off);
            sum = __shfl(sum, 0);
            const float inv = 1.f / sum;
#pragma unroll
            for (int j = 0; j < 5; ++j) mreg[g][j] += ex[j] * inv;

            const float2 cvv =
                ((const float2*)(cv + ((size_t)g * V_CODES + besti) * CV_DIM))[lane];
            ((float2*)(out + n * 256 + g * CV_DIM))[lane] = cvv;
        }
    }

    // --- marginal: wave regs -> LDS atomics -> global atomics ---
#pragma unroll
    for (int g = 0; g < 2; ++g)
#pragma unroll
        for (int j = 0; j < 5; ++j)
            atomicAdd(&sm.e.marg[g * V_CODES + lane + 64 * j], mreg[g][j]);
    __syncthreads();
    for (int i = t; i < 640; i += 512) atomicAdd(marginal + i, sm.e.marg[i]);
}

// ---------------------------------------------------------------------------
// Kernel 2: finalize perplexity from the global marginal (640 floats).
// ---------------------------------------------------------------------------
__global__ __launch_bounds__(640)
void finalize(const float* __restrict__ marginal, float* __restrict__ perp_out) {
    __shared__ float terms[640];
    __shared__ float gsum[2];
    const int t = threadIdx.x;

    const float m = marginal[t] * (1.0f / (float)M_ROWS);
    terms[t] = -m * __logf(m + 1e-7f);
    __syncthreads();

    if (t < 128) {
        const int g = t >> 6, lane = t & 63;
        float e = 0.f;
#pragma unroll
        for (int j = 0; j < 5; ++j) e += terms[g * V_CODES + lane + 64 * j];
#pragma unroll
        for (int off = 32; off; off >>= 1) e += __shfl_down(e, off);
        if (lane == 0) gsum[g] = e;
    }
    __syncthreads();
    if (t == 0) perp_out[0] = __expf(gsum[0]) + __expf(gsum[1]);
}

// ---------------------------------------------------------------------------
extern "C" void kernel_launch(void* const* d_in, const int* in_sizes, int n_in,
                              void* d_out, int out_size, void* d_ws, size_t ws_size,
                              hipStream_t stream) {
    (void)in_sizes; (void)n_in; (void)out_size; (void)ws_size;
    const float* hs = (const float*)d_in[0];   // (8,2048,512) f32
    const float* W  = (const float*)d_in[1];   // (512,640)    f32
    const float* bi = (const float*)d_in[2];   // (640,)       f32
    const float* cv = (const float*)d_in[3];   // (1,640,128)  f32
    const float* gu = (const float*)d_in[4];   // (32768,320)  f32
    float* out = (float*)d_out;                // 16384*256 + 1

    // ws: Wt (640*512 f16 = 640 KB) + marginal (640 f32)
    _Float16* Wt       = (_Float16*)d_ws;
    float*    marginal = (float*)(Wt + (size_t)N_COLS * K_DIM);

    prep<<<41, 256, 0, stream>>>(W, Wt, marginal);
    fused<<<512, 512, 0, stream>>>(hs, Wt, bi, gu, cv, out, marginal);
    finalize<<<1, 640, 0, stream>>>(marginal, out + (size_t)M_ROWS * 256);
}